// Round 4
// baseline (172.204 us; speedup 1.0000x reference)
//
#include <hip/hip_runtime.h>
#include <math.h>

#define NUM_CLASSES 10

typedef __attribute__((ext_vector_type(2))) float f32x2;

// ---- block reduction: wave shuffle (64) -> LDS across waves -> lane 0 ----
__device__ __forceinline__ double block_reduce_sum(double v, double* lds) {
    #pragma unroll
    for (int off = 32; off > 0; off >>= 1)
        v += __shfl_down(v, off, 64);
    int lane = threadIdx.x & 63;
    int wid  = threadIdx.x >> 6;
    int nw   = blockDim.x >> 6;
    if (lane == 0) lds[wid] = v;
    __syncthreads();
    if (wid == 0) {
        v = (lane < nw) ? lds[lane] : 0.0;
        #pragma unroll
        for (int off = 4; off > 0; off >>= 1)
            v += __shfl_down(v, off, 64);
    }
    return v;
}

__device__ __forceinline__ double focal_term(
    const float* __restrict__ logits, const int* __restrict__ targets,
    const int* __restrict__ tissue, const float* __restrict__ cw,
    const float* __restrict__ tw, int r) {
    const float* row = logits + (size_t)r * NUM_CLASSES;
    float l[NUM_CLASSES];
    float m = -INFINITY;
    #pragma unroll
    for (int c = 0; c < NUM_CLASSES; ++c) { l[c] = row[c]; m = fmaxf(m, l[c]); }
    float s = 0.f;
    #pragma unroll
    for (int c = 0; c < NUM_CLASSES; ++c) s += expf(l[c] - m);
    int   t  = targets[r];
    float lp = l[t] - m - logf(s);
    float p  = expf(lp);
    float om = 1.f - p;
    float w  = om * om * cw[t] * tw[tissue[r]];
    return (double)(-w * lp);
}

// 4 fp8 pairs (packed in two ints) -> fp32 dot accumulate
__device__ __forceinline__ float fp8dot4(int a, int b, float d) {
    f32x2 al = __builtin_amdgcn_cvt_pk_f32_fp8(a, false);
    f32x2 ah = __builtin_amdgcn_cvt_pk_f32_fp8(a, true);
    f32x2 bl = __builtin_amdgcn_cvt_pk_f32_fp8(b, false);
    f32x2 bh = __builtin_amdgcn_cvt_pk_f32_fp8(b, true);
    d = fmaf(al.x, bl.x, d); d = fmaf(al.y, bl.y, d);
    d = fmaf(ah.x, bh.x, d); d = fmaf(ah.y, bh.y, d);
    return d;
}

// ---- pack: node record = 64 B line: relu(S) fp8 e4m3 [32 B] + pos [8 B] + pad
// rec viewed as int[16] per node: ints 0..7 = fp8 row, ints 8..9 = pos bits.
__global__ void pack_kernel(const float4* __restrict__ S4,
                            const float2* __restrict__ pos,
                            int* __restrict__ rec_i,
                            int n4, int N) {
    int i = blockIdx.x * blockDim.x + threadIdx.x;
    if (i < n4) {                      // convert one float4 chunk -> one int
        float4 v = S4[i];
        int w = __builtin_amdgcn_cvt_pk_fp8_f32(fmaxf(v.x, 0.f), fmaxf(v.y, 0.f), 0, false);
        w = __builtin_amdgcn_cvt_pk_fp8_f32(fmaxf(v.z, 0.f), fmaxf(v.w, 0.f), w, true);
        int node = i >> 3, sub = i & 7;
        rec_i[node * 16 + sub] = w;
    }
    if (i < N) {                       // drop pos into the same record line
        float2 p = pos[i];
        rec_i[i * 16 + 8] = __float_as_int(p.x);
        rec_i[i * 16 + 9] = __float_as_int(p.y);
    }
}

__device__ __forceinline__ void finalize_and_store(
    double fl, double sp, double* lds_f, double* lds_s,
    double* __restrict__ acc, unsigned* __restrict__ ctr,
    float* __restrict__ out, int B, int E) {
    double bs_f = block_reduce_sum(fl, lds_f);
    double bs_s = block_reduce_sum(sp, lds_s);
    if (threadIdx.x == 0) {
        atomicAdd(&acc[0], bs_f);
        atomicAdd(&acc[1], bs_s);
        __threadfence();
        unsigned done = atomicAdd(ctr, 1u);
        if (done == gridDim.x - 1) {
            __threadfence();
            double cs = atomicAdd(&acc[0], 0.0);
            double ss = atomicAdd(&acc[1], 0.0);
            float cls = (float)(cs / (double)B);
            float spv = (float)(0.01 * ss / (double)E);
            out[0] = cls + spv;
            out[1] = cls;
            out[2] = spv;
        }
    }
}

// ---- main fused kernel: 1 thread/edge, 1 line/node, idx prefetch pipeline
__global__ __launch_bounds__(256, 8) void fused_fp8_kernel(
    const float* __restrict__ logits,
    const int*   __restrict__ targets,
    const int*   __restrict__ tissue,
    const float* __restrict__ cw,
    const float* __restrict__ tw,
    const int4*  __restrict__ rec,     // 4 int4 per node (64 B records)
    const int*   __restrict__ src_idx,
    const int*   __restrict__ dst_idx,
    int B, int E,
    double*      __restrict__ acc,
    unsigned*    __restrict__ ctr,
    float*       __restrict__ out) {

    __shared__ double lds_f[4];
    __shared__ double lds_s[4];
    int gtid   = blockIdx.x * blockDim.x + threadIdx.x;
    int stride = gridDim.x * blockDim.x;

    double fl = 0.0;
    if (gtid < B) fl = focal_term(logits, targets, tissue, cw, tw, gtid);

    double sp = 0.0;
    int e = gtid;
    if (e < E) {
        int s = src_idx[e];
        int d = dst_idx[e];
        while (true) {
            const int4* rs = rec + (size_t)s * 4;
            const int4* rd = rec + (size_t)d * 4;
            // 1 cache line per node: row (2x int4) + pos (float2) same line
            int4  a0 = rs[0], a1 = rs[1];
            int4  b0 = rd[0], b1 = rd[1];
            float2 ps = *(const float2*)(rs + 2);
            float2 pd = *(const float2*)(rd + 2);

            // prefetch next edge's indices past the record gather
            int  en   = e + stride;
            bool more = en < E;
            int  sn = 0, dn = 0;
            if (more) { sn = src_idx[en]; dn = dst_idx[en]; }

            float dot = 0.f;
            dot = fp8dot4(a0.x, b0.x, dot);
            dot = fp8dot4(a0.y, b0.y, dot);
            dot = fp8dot4(a0.z, b0.z, dot);
            dot = fp8dot4(a0.w, b0.w, dot);
            dot = fp8dot4(a1.x, b1.x, dot);
            dot = fp8dot4(a1.y, b1.y, dot);
            dot = fp8dot4(a1.z, b1.z, dot);
            dot = fp8dot4(a1.w, b1.w, dot);

            float dx = ps.x - pd.x, dy = ps.y - pd.y;
            sp += (double)(dot * (dx * dx + dy * dy));

            if (!more) break;
            e = en; s = sn; d = dn;
        }
    }

    finalize_and_store(fl, sp, lds_f, lds_s, acc, ctr, out, B, E);
}

// ---- fallback: fp32 rows direct (only if ws can't hold the pack buffer) ----
__global__ __launch_bounds__(256) void fused_fp32_kernel(
    const float*  __restrict__ logits,
    const int*    __restrict__ targets,
    const int*    __restrict__ tissue,
    const float*  __restrict__ cw,
    const float*  __restrict__ tw,
    const float4* __restrict__ S4,     // fp32 rows: 8 float4 per node
    const float2* __restrict__ pos,
    const int*    __restrict__ src_idx,
    const int*    __restrict__ dst_idx,
    int B, int E,
    double*       __restrict__ acc,
    unsigned*     __restrict__ ctr,
    float*        __restrict__ out) {

    __shared__ double lds_f[4];
    __shared__ double lds_s[4];
    int gtid = blockIdx.x * blockDim.x + threadIdx.x;
    int stride = gridDim.x * blockDim.x;

    double fl = 0.0;
    if (gtid < B) fl = focal_term(logits, targets, tissue, cw, tw, gtid);

    double sp = 0.0;
    for (int e = gtid; e < E; e += stride) {
        int s = src_idx[e], d = dst_idx[e];
        const float4* Sr = S4 + (size_t)s * 8;
        const float4* Dr = S4 + (size_t)d * 8;
        float dot = 0.f;
        #pragma unroll
        for (int c = 0; c < 8; ++c) {
            float4 a = Sr[c], b = Dr[c];
            dot += fmaxf(a.x, 0.f) * fmaxf(b.x, 0.f);
            dot += fmaxf(a.y, 0.f) * fmaxf(b.y, 0.f);
            dot += fmaxf(a.z, 0.f) * fmaxf(b.z, 0.f);
            dot += fmaxf(a.w, 0.f) * fmaxf(b.w, 0.f);
        }
        float2 pp = pos[s], qq = pos[d];
        float dx = pp.x - qq.x, dy = pp.y - qq.y;
        sp += (double)(dot * (dx * dx + dy * dy));
    }
    finalize_and_store(fl, sp, lds_f, lds_s, acc, ctr, out, B, E);
}

extern "C" void kernel_launch(void* const* d_in, const int* in_sizes, int n_in,
                              void* d_out, int out_size, void* d_ws, size_t ws_size,
                              hipStream_t stream) {
    const float* logits  = (const float*)d_in[0];
    const int*   targets = (const int*)  d_in[1];
    const float* S       = (const float*)d_in[2];
    const float* pos     = (const float*)d_in[3];
    const int*   edge    = (const int*)  d_in[4];
    const int*   tissue  = (const int*)  d_in[5];
    const float* cw      = (const float*)d_in[6];
    const float* tw      = (const float*)d_in[7];
    float* out = (float*)d_out;

    int B  = in_sizes[1];
    int E  = in_sizes[4] / 2;
    int nS = in_sizes[2];            // N * 32
    int N  = in_sizes[3] / 2;        // nodes
    int n4 = nS / 4;

    double*   acc = (double*)d_ws;
    unsigned* ctr = (unsigned*)((char*)d_ws + 16);
    hipMemsetAsync(d_ws, 0, 24, stream);

    size_t rec_bytes = (size_t)N * 64;
    const int GRID = 2048;           // 8 blocks/CU -> 32 waves/CU resident

    if (ws_size >= 256 + rec_bytes) {
        int* rec = (int*)((char*)d_ws + 256);
        int packN = (n4 > N) ? n4 : N;
        pack_kernel<<<(packN + 255) / 256, 256, 0, stream>>>(
            (const float4*)S, (const float2*)pos, rec, n4, N);
        fused_fp8_kernel<<<GRID, 256, 0, stream>>>(
            logits, targets, tissue, cw, tw,
            (const int4*)rec, edge, edge + E,
            B, E, acc, ctr, out);
    } else {
        fused_fp32_kernel<<<GRID, 256, 0, stream>>>(
            logits, targets, tissue, cw, tw,
            (const float4*)S, (const float2*)pos, edge, edge + E,
            B, E, acc, ctr, out);
    }
}

// Round 5
// 108.506 us; speedup vs baseline: 1.5871x; 1.5871x over previous
//
#include <hip/hip_runtime.h>
#include <math.h>

#define NUM_CLASSES 10

typedef __attribute__((ext_vector_type(2))) float f32x2;

// ---- block reduction: wave shuffle (64) -> LDS across waves -> lane 0 ----
__device__ __forceinline__ double block_reduce_sum(double v, double* lds) {
    #pragma unroll
    for (int off = 32; off > 0; off >>= 1)
        v += __shfl_down(v, off, 64);
    int lane = threadIdx.x & 63;
    int wid  = threadIdx.x >> 6;
    int nw   = blockDim.x >> 6;
    if (lane == 0) lds[wid] = v;
    __syncthreads();
    if (wid == 0) {
        v = (lane < nw) ? lds[lane] : 0.0;
        #pragma unroll
        for (int off = 4; off > 0; off >>= 1)
            v += __shfl_down(v, off, 64);
    }
    return v;
}

__device__ __forceinline__ double focal_term(
    const float* __restrict__ logits, const int* __restrict__ targets,
    const int* __restrict__ tissue, const float* __restrict__ cw,
    const float* __restrict__ tw, int r) {
    const float* row = logits + (size_t)r * NUM_CLASSES;
    float l[NUM_CLASSES];
    float m = -INFINITY;
    #pragma unroll
    for (int c = 0; c < NUM_CLASSES; ++c) { l[c] = row[c]; m = fmaxf(m, l[c]); }
    float s = 0.f;
    #pragma unroll
    for (int c = 0; c < NUM_CLASSES; ++c) s += expf(l[c] - m);
    int   t  = targets[r];
    float lp = l[t] - m - logf(s);
    float p  = expf(lp);
    float om = 1.f - p;
    float w  = om * om * cw[t] * tw[tissue[r]];
    return (double)(-w * lp);
}

// 4 fp8 pairs (packed in two ints) -> fp32 dot accumulate
__device__ __forceinline__ float fp8dot4(int a, int b, float d) {
    f32x2 al = __builtin_amdgcn_cvt_pk_f32_fp8(a, false);
    f32x2 ah = __builtin_amdgcn_cvt_pk_f32_fp8(a, true);
    f32x2 bl = __builtin_amdgcn_cvt_pk_f32_fp8(b, false);
    f32x2 bh = __builtin_amdgcn_cvt_pk_f32_fp8(b, true);
    d = fmaf(al.x, bl.x, d); d = fmaf(al.y, bl.y, d);
    d = fmaf(ah.x, bh.x, d); d = fmaf(ah.y, bh.y, d);
    return d;
}

__device__ __forceinline__ float fp8dot32(int4 a0, int4 a1, int4 b0, int4 b1) {
    float dot = 0.f;
    dot = fp8dot4(a0.x, b0.x, dot);
    dot = fp8dot4(a0.y, b0.y, dot);
    dot = fp8dot4(a0.z, b0.z, dot);
    dot = fp8dot4(a0.w, b0.w, dot);
    dot = fp8dot4(a1.x, b1.x, dot);
    dot = fp8dot4(a1.y, b1.y, dot);
    dot = fp8dot4(a1.z, b1.z, dot);
    dot = fp8dot4(a1.w, b1.w, dot);
    return dot;
}

// ---- pack: node record = 64 B line: relu(S) fp8 e4m3 [32 B] + pos [8 B] + pad
__global__ void pack_kernel(const float4* __restrict__ S4,
                            const float2* __restrict__ pos,
                            int* __restrict__ rec_i,
                            int n4, int N) {
    int i = blockIdx.x * blockDim.x + threadIdx.x;
    if (i < n4) {
        float4 v = S4[i];
        int w = __builtin_amdgcn_cvt_pk_fp8_f32(fmaxf(v.x, 0.f), fmaxf(v.y, 0.f), 0, false);
        w = __builtin_amdgcn_cvt_pk_fp8_f32(fmaxf(v.z, 0.f), fmaxf(v.w, 0.f), w, true);
        int node = i >> 3, sub = i & 7;
        rec_i[node * 16 + sub] = w;
    }
    if (i < N) {
        float2 p = pos[i];
        rec_i[i * 16 + 8] = __float_as_int(p.x);
        rec_i[i * 16 + 9] = __float_as_int(p.y);
    }
}

// ---- main kernel: 4 edges per thread, ALL loads batched before ANY compute,
//      no atomics / no fences — per-block partials to d_ws.
__global__ __launch_bounds__(256) void spatial_focal_kernel(
    const float* __restrict__ logits,
    const int*   __restrict__ targets,
    const int*   __restrict__ tissue,
    const float* __restrict__ cw,
    const float* __restrict__ tw,
    const int4*  __restrict__ rec,     // 4 int4 per node (64 B records)
    const int*   __restrict__ src_idx,
    const int*   __restrict__ dst_idx,
    int B, int E, int T,               // T = total threads
    double*      __restrict__ part_f,
    double*      __restrict__ part_s) {

    __shared__ double lds_f[4];
    __shared__ double lds_s[4];
    int gtid = blockIdx.x * blockDim.x + threadIdx.x;

    double fl = 0.0;
    if (gtid < B) fl = focal_term(logits, targets, tissue, cw, tw, gtid);

    int e0 = gtid, e1 = gtid + T, e2 = gtid + 2 * T, e3 = gtid + 3 * T;
    float m0 = (e0 < E) ? 1.f : 0.f;
    float m1 = (e1 < E) ? 1.f : 0.f;
    float m2 = (e2 < E) ? 1.f : 0.f;
    float m3 = (e3 < E) ? 1.f : 0.f;
    int e0c = (e0 < E) ? e0 : 0;
    int e1c = (e1 < E) ? e1 : 0;
    int e2c = (e2 < E) ? e2 : 0;
    int e3c = (e3 < E) ? e3 : 0;

    // --- all index loads (coalesced) ---
    int s0 = src_idx[e0c], d0 = dst_idx[e0c];
    int s1 = src_idx[e1c], d1 = dst_idx[e1c];
    int s2 = src_idx[e2c], d2 = dst_idx[e2c];
    int s3 = src_idx[e3c], d3 = dst_idx[e3c];

    // --- all gathers issued back-to-back: 24 independent lines in flight ---
    const int4 *q;
    q = rec + (size_t)s0 * 4; int4 as0 = q[0], as0h = q[1]; float2 ps0 = *(const float2*)(q + 2);
    q = rec + (size_t)d0 * 4; int4 bs0 = q[0], bs0h = q[1]; float2 pd0 = *(const float2*)(q + 2);
    q = rec + (size_t)s1 * 4; int4 as1 = q[0], as1h = q[1]; float2 ps1 = *(const float2*)(q + 2);
    q = rec + (size_t)d1 * 4; int4 bs1 = q[0], bs1h = q[1]; float2 pd1 = *(const float2*)(q + 2);
    q = rec + (size_t)s2 * 4; int4 as2 = q[0], as2h = q[1]; float2 ps2 = *(const float2*)(q + 2);
    q = rec + (size_t)d2 * 4; int4 bs2 = q[0], bs2h = q[1]; float2 pd2 = *(const float2*)(q + 2);
    q = rec + (size_t)s3 * 4; int4 as3 = q[0], as3h = q[1]; float2 ps3 = *(const float2*)(q + 2);
    q = rec + (size_t)d3 * 4; int4 bs3 = q[0], bs3h = q[1]; float2 pd3 = *(const float2*)(q + 2);

    // --- compute all 4 edges ---
    double sp = 0.0;
    float dx, dy, w;
    w = fp8dot32(as0, as0h, bs0, bs0h);
    dx = ps0.x - pd0.x; dy = ps0.y - pd0.y;
    sp += (double)(m0 * w * (dx * dx + dy * dy));
    w = fp8dot32(as1, as1h, bs1, bs1h);
    dx = ps1.x - pd1.x; dy = ps1.y - pd1.y;
    sp += (double)(m1 * w * (dx * dx + dy * dy));
    w = fp8dot32(as2, as2h, bs2, bs2h);
    dx = ps2.x - pd2.x; dy = ps2.y - pd2.y;
    sp += (double)(m2 * w * (dx * dx + dy * dy));
    w = fp8dot32(as3, as3h, bs3, bs3h);
    dx = ps3.x - pd3.x; dy = ps3.y - pd3.y;
    sp += (double)(m3 * w * (dx * dx + dy * dy));

    double bs_f = block_reduce_sum(fl, lds_f);
    double bs_s = block_reduce_sum(sp, lds_s);
    if (threadIdx.x == 0) {
        part_f[blockIdx.x] = bs_f;   // plain stores, no atomics, no fences
        part_s[blockIdx.x] = bs_s;
    }
}

// ---- final reduce: one block sums the per-block partials ----
__global__ void reduce_kernel(const double* __restrict__ part_f,
                              const double* __restrict__ part_s,
                              int nb, float* __restrict__ out, int B, int E) {
    __shared__ double lds_f[4];
    __shared__ double lds_s[4];
    double f = 0.0, s = 0.0;
    for (int i = threadIdx.x; i < nb; i += blockDim.x) {
        f += part_f[i];
        s += part_s[i];
    }
    double tf = block_reduce_sum(f, lds_f);
    double ts = block_reduce_sum(s, lds_s);
    if (threadIdx.x == 0) {
        float cls = (float)(tf / (double)B);
        float spv = (float)(0.01 * ts / (double)E);
        out[0] = cls + spv;
        out[1] = cls;
        out[2] = spv;
    }
}

// ---- fallback: fp32 direct (only if ws can't hold rec + partials) ----
__global__ __launch_bounds__(256) void fallback_kernel(
    const float*  __restrict__ logits,
    const int*    __restrict__ targets,
    const int*    __restrict__ tissue,
    const float*  __restrict__ cw,
    const float*  __restrict__ tw,
    const float4* __restrict__ S4,
    const float2* __restrict__ pos,
    const int*    __restrict__ src_idx,
    const int*    __restrict__ dst_idx,
    int B, int E, int T,
    double*       __restrict__ part_f,
    double*       __restrict__ part_s) {
    __shared__ double lds_f[4];
    __shared__ double lds_s[4];
    int gtid = blockIdx.x * blockDim.x + threadIdx.x;
    double fl = 0.0;
    if (gtid < B) fl = focal_term(logits, targets, tissue, cw, tw, gtid);
    double sp = 0.0;
    for (int e = gtid; e < E; e += T) {
        int s = src_idx[e], d = dst_idx[e];
        const float4* Sr = S4 + (size_t)s * 8;
        const float4* Dr = S4 + (size_t)d * 8;
        float dot = 0.f;
        #pragma unroll
        for (int c = 0; c < 8; ++c) {
            float4 a = Sr[c], b = Dr[c];
            dot += fmaxf(a.x, 0.f) * fmaxf(b.x, 0.f);
            dot += fmaxf(a.y, 0.f) * fmaxf(b.y, 0.f);
            dot += fmaxf(a.z, 0.f) * fmaxf(b.z, 0.f);
            dot += fmaxf(a.w, 0.f) * fmaxf(b.w, 0.f);
        }
        float2 pp = pos[s], qq = pos[d];
        float dx = pp.x - qq.x, dy = pp.y - qq.y;
        sp += (double)(dot * (dx * dx + dy * dy));
    }
    double bs_f = block_reduce_sum(fl, lds_f);
    double bs_s = block_reduce_sum(sp, lds_s);
    if (threadIdx.x == 0) {
        part_f[blockIdx.x] = bs_f;
        part_s[blockIdx.x] = bs_s;
    }
}

extern "C" void kernel_launch(void* const* d_in, const int* in_sizes, int n_in,
                              void* d_out, int out_size, void* d_ws, size_t ws_size,
                              hipStream_t stream) {
    const float* logits  = (const float*)d_in[0];
    const int*   targets = (const int*)  d_in[1];
    const float* S       = (const float*)d_in[2];
    const float* pos     = (const float*)d_in[3];
    const int*   edge    = (const int*)  d_in[4];
    const int*   tissue  = (const int*)  d_in[5];
    const float* cw      = (const float*)d_in[6];
    const float* tw      = (const float*)d_in[7];
    float* out = (float*)d_out;

    int B  = in_sizes[1];
    int E  = in_sizes[4] / 2;
    int nS = in_sizes[2];            // N * 32
    int N  = in_sizes[3] / 2;        // nodes
    int n4 = nS / 4;

    const int EDGES_PER_THREAD = 4;
    int nb = (E + 256 * EDGES_PER_THREAD - 1) / (256 * EDGES_PER_THREAD);
    int T  = nb * 256;

    size_t rec_bytes = (size_t)N * 64;
    size_t part_off  = (rec_bytes + 255) & ~(size_t)255;
    size_t need      = part_off + (size_t)2 * nb * sizeof(double) + 256;

    if (ws_size >= need) {
        int*    rec    = (int*)d_ws;
        double* part_f = (double*)((char*)d_ws + part_off);
        double* part_s = part_f + nb;
        int packN = (n4 > N) ? n4 : N;
        pack_kernel<<<(packN + 255) / 256, 256, 0, stream>>>(
            (const float4*)S, (const float2*)pos, rec, n4, N);
        spatial_focal_kernel<<<nb, 256, 0, stream>>>(
            logits, targets, tissue, cw, tw,
            (const int4*)rec, edge, edge + E,
            B, E, T, part_f, part_s);
        reduce_kernel<<<1, 256, 0, stream>>>(part_f, part_s, nb, out, B, E);
    } else {
        // fallback: partials only (needs 2*nb doubles)
        int nb2 = 2048;
        int T2  = nb2 * 256;
        double* part_f = (double*)d_ws;
        double* part_s = part_f + nb2;
        fallback_kernel<<<nb2, 256, 0, stream>>>(
            logits, targets, tissue, cw, tw,
            (const float4*)S, (const float2*)pos, edge, edge + E,
            B, E, T2, part_f, part_s);
        reduce_kernel<<<1, 256, 0, stream>>>(part_f, part_s, nb2, out, B, E);
    }
}